// Round 4
// baseline (80.323 us; speedup 1.0000x reference)
//
#include <hip/hip_runtime.h>

#define T_DIM 20
#define K_DIM 50
#define V_DIM 50000
#define D_DIM 200
#define NEG_TOPK 20
#define M_DIM (K_DIM * NEG_TOPK)   // 1000 candidates per time slice
#define TEMP_INV (1.0f / 0.07f)
#define POOL_CAP 512
#define STATIC_THR 3.0f            // pool keeps all elements >= 3.0

// monotone key: order(key) == (value desc, index asc) matches jax.lax.top_k
__device__ __forceinline__ unsigned long long make_key(float f, int idx) {
  unsigned u  = __float_as_uint(f);
  unsigned mv = ((int)u < 0) ? ~u : (u | 0x80000000u);
  return ((unsigned long long)mv << 32) |
         (unsigned long long)(0xFFFFFFFFu - (unsigned)idx);
}

__device__ __forceinline__ unsigned long long wave_max_u64(unsigned long long k) {
#pragma unroll
  for (int off = 32; off; off >>= 1) {
    unsigned long long o = __shfl_xor(k, off, 64);
    if (o > k) k = o;
  }
  return k;
}

__device__ __forceinline__ float agent_load_f(const float* p) {
  return __hip_atomic_load(p, __ATOMIC_RELAXED, __HIP_MEMORY_SCOPE_AGENT);
}
__device__ __forceinline__ int agent_load_i(const int* p) {
  return __hip_atomic_load(p, __ATOMIC_RELAXED, __HIP_MEMORY_SCOPE_AGENT);
}
__device__ __forceinline__ void agent_store_f(float* p, float v) {
  __hip_atomic_store(p, v, __ATOMIC_RELAXED, __HIP_MEMORY_SCOPE_AGENT);
}
__device__ __forceinline__ void agent_store_i(int* p, int v) {
  __hip_atomic_store(p, v, __ATOMIC_RELAXED, __HIP_MEMORY_SCOPE_AGENT);
}

// ---------------------------------------------------------------------------
// Kernel 1: exact top-20 per row = t*K+k.
// Scan: 1 cmp/element; elements >= 3.0 go to an LDS pool (E[|pool|]~67).
// If 20 <= |pool| <= 512 the exact top-20 is in the pool (if >=20 elements
// are >= thr, the 20th-largest >= thr). Selection on wave 0 only, barrier-
// free. Fallback (<20 or >512): exact 20-round block-wide rescan (L2-hot).
// Block 0 also re-zeroes the completion counter for kernel 2 (stream order
// guarantees visibility at the kernel boundary).
// ---------------------------------------------------------------------------
__global__ __launch_bounds__(512) void topk_kernel(const float* __restrict__ beta,
                                                   int* __restrict__ topk_idx,
                                                   int* __restrict__ counter) {
  const int row  = blockIdx.x;          // 0..999
  const int tid  = threadIdx.x;
  const int lane = tid & 63;
  const int wid  = tid >> 6;
  const float4* __restrict__ b4 = (const float4*)(beta + (size_t)row * V_DIM);

  if (row == 0 && tid == 0) *counter = 0;

  __shared__ unsigned long long pool[POOL_CAP];
  __shared__ int cnt;
  __shared__ unsigned long long wmax[8];
  if (tid == 0) cnt = 0;
  __syncthreads();

  for (int i = tid; i < V_DIM / 4; i += 512) {
    float4 v = b4[i];
    const int base = i * 4;
#pragma unroll
    for (int e = 0; e < 4; ++e) {
      float f = (e == 0) ? v.x : (e == 1) ? v.y : (e == 2) ? v.z : v.w;
      if (f >= STATIC_THR) {
        int p = atomicAdd(&cnt, 1);
        if (p < POOL_CAP) pool[p] = make_key(f, base + e);
      }
    }
  }
  __syncthreads();
  const int count = cnt;

  if (count >= NEG_TOPK && count <= POOL_CAP) {
    if (wid != 0) return;              // selection is wave-0-only, no barriers
    unsigned long long kk[8];
#pragma unroll
    for (int j = 0; j < 8; ++j) {
      int p = lane + (j << 6);
      kk[j] = (p < count) ? pool[p] : 0ull;
    }
    unsigned long long kprev = ~0ull;
    for (int r = 0; r < NEG_TOPK; ++r) {
      unsigned long long b = 0ull;
#pragma unroll
      for (int j = 0; j < 8; ++j)
        if (kk[j] < kprev && kk[j] > b) b = kk[j];
      b = wave_max_u64(b);
      if (lane == 0)
        topk_idx[row * NEG_TOPK + r] =
            (int)(0xFFFFFFFFu - (unsigned)(b & 0xFFFFFFFFull));
      kprev = b;
    }
  } else {
    // ---- fallback: 20 rounds of block argmax over the row (L2-hot) ----
    unsigned long long kprev = ~0ull;
    for (int r = 0; r < NEG_TOPK; ++r) {
      unsigned long long b = 0ull;
      for (int i = tid; i < V_DIM / 4; i += 512) {
        float4 v = b4[i];
        const int base = i * 4;
#pragma unroll
        for (int e = 0; e < 4; ++e) {
          float f = (e == 0) ? v.x : (e == 1) ? v.y : (e == 2) ? v.z : v.w;
          unsigned long long k = make_key(f, base + e);
          if (k < kprev && k > b) b = k;
        }
      }
      b = wave_max_u64(b);
      if (lane == 0) wmax[wid] = b;
      __syncthreads();
      unsigned long long bmax = wmax[0];
#pragma unroll
      for (int w = 1; w < 8; ++w) bmax = wmax[w] > bmax ? wmax[w] : bmax;
      if (tid == 0)
        topk_idx[row * NEG_TOPK + r] =
            (int)(0xFFFFFFFFu - (unsigned)(bmax & 0xFFFFFFFFull));
      kprev = bmax;
      __syncthreads();
    }
  }
}

// ---------------------------------------------------------------------------
// Kernel 2 (fused): per row = t*K+k --
//  (a) rebuild t's unique valid candidate set in LDS (wc==0, set semantics;
//      redundant across the 50 k-blocks of a t, but L2-hot and cheap),
//  (b) coalesced 8-lane-cooperative gather + dot + logsumexp,
//  (c) agent-scope store of lse[row]; last finished block (ticket pattern,
//      rocPRIM-style) reduces all 1000 lse values to the final scalar.
// Deterministic: only the last block computes the scalar, fixed sum order.
// ---------------------------------------------------------------------------
#define BM_WORDS ((V_DIM + 31) / 32)    // 1563
__global__ __launch_bounds__(256) void fused_lse_kernel(const int* __restrict__ wc,
                                                        const int* __restrict__ topk,
                                                        const float* __restrict__ temb,
                                                        const float* __restrict__ wemb,
                                                        float* __restrict__ lse,
                                                        int* __restrict__ hasv,
                                                        int* __restrict__ counter,
                                                        float* __restrict__ out) {
  const int row  = blockIdx.x;          // 0..999
  const int t    = row / K_DIM;
  const int tid  = threadIdx.x;
  const int lane = tid & 63;
  const int wid  = tid >> 6;

  __shared__ unsigned bm[BM_WORDS];
  __shared__ int      vl[M_DIM];
  __shared__ float    sim[M_DIM];
  __shared__ float4   tvs[D_DIM / 4];
  __shared__ float    rbuf[8];
  __shared__ int      cnt;
  __shared__ int      ticket_s;

  for (int i = tid; i < BM_WORDS; i += 256) bm[i] = 0u;
  if (tid == 0) cnt = 0;
  if (tid < D_DIM / 4)
    tvs[tid] = ((const float4*)(temb + (size_t)row * D_DIM))[tid];
  __syncthreads();

  // (a) dedup + zero-count filter into LDS list
  for (int c = tid; c < M_DIM; c += 256) {
    int w = topk[t * M_DIM + c];
    if (wc[t * V_DIM + w] == 0) {
      unsigned bit = 1u << (w & 31);
      unsigned old = atomicOr(&bm[w >> 5], bit);
      if (!(old & bit)) {
        int p = atomicAdd(&cnt, 1);
        vl[p] = w;
      }
    }
  }
  __syncthreads();
  const int count = cnt;

  float lval = 0.0f;
  if (count > 0) {
    // (b) 8-lane-cooperative coalesced gather + dot
    const int l7 = lane & 7;
    const int g  = lane >> 3;
    for (int c0 = wid * 8; c0 < count; c0 += 32) {
      const int c = c0 + g;
      float acc = 0.f;
      if (c < count) {
        const int w = vl[c];
        const float4* __restrict__ wr = (const float4*)(wemb + (size_t)w * D_DIM);
#pragma unroll
        for (int m = 0; m < 6; ++m) {
          const int d = l7 + (m << 3);
          float4 a = tvs[d];
          float4 b = wr[d];
          acc = fmaf(a.x, b.x, acc);
          acc = fmaf(a.y, b.y, acc);
          acc = fmaf(a.z, b.z, acc);
          acc = fmaf(a.w, b.w, acc);
        }
        if (l7 < 2) {
          const int d = l7 + 48;
          float4 a = tvs[d];
          float4 b = wr[d];
          acc = fmaf(a.x, b.x, acc);
          acc = fmaf(a.y, b.y, acc);
          acc = fmaf(a.z, b.z, acc);
          acc = fmaf(a.w, b.w, acc);
        }
      }
      acc += __shfl_xor(acc, 1, 64);
      acc += __shfl_xor(acc, 2, 64);
      acc += __shfl_xor(acc, 4, 64);
      if (l7 == 0 && c < count) sim[c] = acc * TEMP_INV;
    }
    __syncthreads();

    float m = -3.0e38f;
    for (int c = tid; c < count; c += 256) m = fmaxf(m, sim[c]);
#pragma unroll
    for (int off = 32; off; off >>= 1) m = fmaxf(m, __shfl_xor(m, off, 64));
    if (lane == 0) rbuf[wid] = m;
    __syncthreads();
    m = fmaxf(fmaxf(rbuf[0], rbuf[1]), fmaxf(rbuf[2], rbuf[3]));

    float s = 0.f;
    for (int c = tid; c < count; c += 256) s += expf(sim[c] - m);
#pragma unroll
    for (int off = 32; off; off >>= 1) s += __shfl_xor(s, off, 64);
    if (lane == 0) rbuf[4 + wid] = s;
    __syncthreads();
    lval = rbuf[4] + rbuf[5] + rbuf[6] + rbuf[7];
    lval = m + logf(lval);
  } else {
    __syncthreads();   // keep barrier count uniform with the count>0 path? (no barrier inside if on other path is fine since block-uniform)
  }

  // (c) publish + last-block final reduction
  if (tid == 0) {
    agent_store_f(&lse[row], lval);
    if (row % K_DIM == 0) agent_store_i(&hasv[t], count > 0 ? 1 : 0);
    __threadfence();
    ticket_s = atomicAdd(counter, 1);
  }
  __syncthreads();

  if (ticket_s == T_DIM * K_DIM - 1) {
    __threadfence();
    for (int r = tid; r < T_DIM * K_DIM; r += 256)
      sim[r] = agent_load_f(&lse[r]);           // reuse sim LDS
    __syncthreads();
    float loss = 0.f, flag = 0.f;
    if (tid < T_DIM) {
      if (agent_load_i(&hasv[tid]) != 0) {
        float s = 0.f;
        for (int k = 0; k < K_DIM; ++k) s += sim[tid * K_DIM + k];
        loss = s * (1.0f / K_DIM);
        flag = 1.f;
      }
    }
    if (wid == 0) {
#pragma unroll
      for (int off = 32; off; off >>= 1) {
        loss += __shfl_down(loss, off, 64);
        flag += __shfl_down(flag, off, 64);
      }
      if (tid == 0)
        out[0] = (flag > 0.f) ? loss * (1.0f / fmaxf(flag, 1.f)) : 0.f;
    }
  }
}

// ---------------------------------------------------------------------------
extern "C" void kernel_launch(void* const* d_in, const int* in_sizes, int n_in,
                              void* d_out, int out_size, void* d_ws, size_t ws_size,
                              hipStream_t stream) {
  const int*   wc   = (const int*)d_in[0];    // time_wordcount [T,V] int32
  const float* beta = (const float*)d_in[1];  // beta [T,K,V] f32
  const float* temb = (const float*)d_in[2];  // topic_embeddings [T,K,D] f32
  const float* wemb = (const float*)d_in[3];  // word_embeddings [V,D] f32

  // ws layout: topk 80000B | lse 4000B | hasv 128B | counter 128B
  char* ws = (char*)d_ws;
  int*   topk_idx = (int*)(ws + 0);
  float* lse      = (float*)(ws + 80000);
  int*   hasv     = (int*)(ws + 84000);
  int*   counter  = (int*)(ws + 84128);
  float* out      = (float*)d_out;

  topk_kernel<<<T_DIM * K_DIM, 512, 0, stream>>>(beta, topk_idx, counter);
  fused_lse_kernel<<<T_DIM * K_DIM, 256, 0, stream>>>(wc, topk_idx, temb, wemb,
                                                      lse, hasv, counter, out);
}

// Round 5
// 71.452 us; speedup vs baseline: 1.1241x; 1.1241x over previous
//
#include <hip/hip_runtime.h>

#define T_DIM 20
#define K_DIM 50
#define V_DIM 50000
#define D_DIM 200
#define NEG_TOPK 20
#define M_DIM (K_DIM * NEG_TOPK)   // 1000 candidates per time slice
#define TEMP_INV (1.0f / 0.07f)
#define POOL_CAP 512
#define STATIC_THR 3.0f            // pool keeps all elements >= 3.0

typedef float f32x4 __attribute__((ext_vector_type(4)));

// monotone key: order(key) == (value desc, index asc) matches jax.lax.top_k
__device__ __forceinline__ unsigned long long make_key(float f, int idx) {
  unsigned u  = __float_as_uint(f);
  unsigned mv = ((int)u < 0) ? ~u : (u | 0x80000000u);
  return ((unsigned long long)mv << 32) |
         (unsigned long long)(0xFFFFFFFFu - (unsigned)idx);
}

__device__ __forceinline__ unsigned long long wave_max_u64(unsigned long long k) {
#pragma unroll
  for (int off = 32; off; off >>= 1) {
    unsigned long long o = __shfl_xor(k, off, 64);
    if (o > k) k = o;
  }
  return k;
}

// ---------------------------------------------------------------------------
// Kernel 1: exact top-20 per row = t*K+k.
// Scan: nontemporal float4 stream (beta is single-use per call; skip cache
// allocation), fmax-tree predicate (3 vmax + 1 cmp common path); elements
// >= 3.0 appended to LDS pool (E[|pool|]~67, Poisson). If 20<=|pool|<=512
// the exact top-20 is in the pool (if >=20 elements are >= thr, the
// 20th-largest >= thr). Selection on wave 0 only, barrier-free; waves 1..7
// exit. Fallback (<20 or >512 pooled): exact 20-round block rescan (cached).
// ---------------------------------------------------------------------------
__global__ __launch_bounds__(512) void topk_kernel(const float* __restrict__ beta,
                                                   int* __restrict__ topk_idx) {
  const int row  = blockIdx.x;          // 0..999
  const int tid  = threadIdx.x;
  const int lane = tid & 63;
  const int wid  = tid >> 6;
  const f32x4* __restrict__ b4 = (const f32x4*)(beta + (size_t)row * V_DIM);

  __shared__ unsigned long long pool[POOL_CAP];
  __shared__ int cnt;
  __shared__ unsigned long long wmax[8];
  if (tid == 0) cnt = 0;
  __syncthreads();

  // ---- scan: 1 fmax-tree compare per float4, rare append ----
  for (int i = tid; i < V_DIM / 4; i += 512) {
    f32x4 v = __builtin_nontemporal_load(b4 + i);
    const int base = i * 4;
    float mx = fmaxf(fmaxf(v.x, v.y), fmaxf(v.z, v.w));
    if (mx >= STATIC_THR) {
#pragma unroll
      for (int e = 0; e < 4; ++e) {
        float f = (e == 0) ? v.x : (e == 1) ? v.y : (e == 2) ? v.z : v.w;
        if (f >= STATIC_THR) {
          int p = atomicAdd(&cnt, 1);
          if (p < POOL_CAP) pool[p] = make_key(f, base + e);
        }
      }
    }
  }
  __syncthreads();
  const int count = cnt;

  if (count >= NEG_TOPK && count <= POOL_CAP) {
    if (wid != 0) return;              // selection is wave-0-only, no barriers
    unsigned long long kk[8];
#pragma unroll
    for (int j = 0; j < 8; ++j) {
      int p = lane + (j << 6);
      kk[j] = (p < count) ? pool[p] : 0ull;
    }
    unsigned long long kprev = ~0ull;
    for (int r = 0; r < NEG_TOPK; ++r) {
      unsigned long long b = 0ull;
#pragma unroll
      for (int j = 0; j < 8; ++j)
        if (kk[j] < kprev && kk[j] > b) b = kk[j];
      b = wave_max_u64(b);
      if (lane == 0)
        topk_idx[row * NEG_TOPK + r] =
            (int)(0xFFFFFFFFu - (unsigned)(b & 0xFFFFFFFFull));
      kprev = b;
    }
  } else {
    // ---- fallback: 20 rounds of block argmax over the row (cached) ----
    unsigned long long kprev = ~0ull;
    for (int r = 0; r < NEG_TOPK; ++r) {
      unsigned long long b = 0ull;
      for (int i = tid; i < V_DIM / 4; i += 512) {
        f32x4 v = b4[i];
        const int base = i * 4;
#pragma unroll
        for (int e = 0; e < 4; ++e) {
          float f = (e == 0) ? v.x : (e == 1) ? v.y : (e == 2) ? v.z : v.w;
          unsigned long long k = make_key(f, base + e);
          if (k < kprev && k > b) b = k;
        }
      }
      b = wave_max_u64(b);
      if (lane == 0) wmax[wid] = b;
      __syncthreads();
      unsigned long long bmax = wmax[0];
#pragma unroll
      for (int w = 1; w < 8; ++w) bmax = wmax[w] > bmax ? wmax[w] : bmax;
      if (tid == 0)
        topk_idx[row * NEG_TOPK + r] =
            (int)(0xFFFFFFFFu - (unsigned)(bmax & 0xFFFFFFFFull));
      kprev = bmax;
      __syncthreads();
    }
  }
}

// ---------------------------------------------------------------------------
// Kernel 2: per time slice t, unique valid candidates (wc==0, set semantics;
// which duplicate survives is irrelevant — identical sim rows).
// ---------------------------------------------------------------------------
#define BM_WORDS ((V_DIM + 31) / 32)    // 1563
__global__ __launch_bounds__(512) void build_valid_kernel(const int* __restrict__ wc,
                                                          const int* __restrict__ topk,
                                                          int* __restrict__ vlist,
                                                          int* __restrict__ vcnt) {
  const int t = blockIdx.x;
  __shared__ unsigned bm[BM_WORDS];
  __shared__ int cnt;
  for (int i = threadIdx.x; i < BM_WORDS; i += 512) bm[i] = 0u;
  if (threadIdx.x == 0) cnt = 0;
  __syncthreads();
  for (int c = threadIdx.x; c < M_DIM; c += 512) {
    int w = topk[t * M_DIM + c];
    if (wc[t * V_DIM + w] == 0) {
      unsigned bit = 1u << (w & 31);
      unsigned old = atomicOr(&bm[w >> 5], bit);
      if (!(old & bit)) {
        int p = atomicAdd(&cnt, 1);
        vlist[t * M_DIM + p] = w;
      }
    }
  }
  __syncthreads();
  if (threadIdx.x == 0) vcnt[t] = cnt;
}

// ---------------------------------------------------------------------------
// Kernel 3: per row = t*K+k, logsumexp over valid candidates of
// dot(topic_emb[t,k,:], word_emb[w,:]) / 0.07.
// Gather is 8-lane-cooperative: lanes 8g..8g+7 read 128B-contiguous chunks
// of candidate row (c0+g) -> 8 rows per wave-load, coalesced; dot reduced
// across the 8-lane group via shfl_xor.
// ---------------------------------------------------------------------------
__global__ __launch_bounds__(256) void lse_kernel(const float* __restrict__ temb,
                                                  const float* __restrict__ wemb,
                                                  const int* __restrict__ vlist,
                                                  const int* __restrict__ vcnt,
                                                  float* __restrict__ lse_out) {
  const int row  = blockIdx.x;
  const int t    = row / K_DIM;
  const int tid  = threadIdx.x;
  const int lane = tid & 63;
  const int wid  = tid >> 6;
  const int cnt  = vcnt[t];

  __shared__ float4 tvs[D_DIM / 4];  // 50 float4: topic embedding row
  __shared__ float  sim[M_DIM];
  __shared__ float  rbuf[8];

  if (cnt == 0) {
    if (tid == 0) lse_out[row] = 0.0f;
    return;
  }

  if (tid < D_DIM / 4)
    tvs[tid] = ((const float4*)(temb + (size_t)row * D_DIM))[tid];
  __syncthreads();

  const int l7 = lane & 7;
  const int g  = lane >> 3;          // candidate sub-slot 0..7 within wave
  for (int c0 = wid * 8; c0 < cnt; c0 += 32) {
    const int c = c0 + g;
    float acc = 0.f;
    if (c < cnt) {
      const int w = vlist[t * M_DIM + c];
      const float4* __restrict__ wr = (const float4*)(wemb + (size_t)w * D_DIM);
#pragma unroll
      for (int m = 0; m < 6; ++m) {        // d = l7 + 8m, always < 50 for m<6
        const int d = l7 + (m << 3);
        float4 a = tvs[d];
        float4 b = wr[d];
        acc = fmaf(a.x, b.x, acc);
        acc = fmaf(a.y, b.y, acc);
        acc = fmaf(a.z, b.z, acc);
        acc = fmaf(a.w, b.w, acc);
      }
      if (l7 < 2) {                        // d = l7 + 48 in {48,49}
        const int d = l7 + 48;
        float4 a = tvs[d];
        float4 b = wr[d];
        acc = fmaf(a.x, b.x, acc);
        acc = fmaf(a.y, b.y, acc);
        acc = fmaf(a.z, b.z, acc);
        acc = fmaf(a.w, b.w, acc);
      }
    }
    acc += __shfl_xor(acc, 1, 64);
    acc += __shfl_xor(acc, 2, 64);
    acc += __shfl_xor(acc, 4, 64);
    if (l7 == 0 && c < cnt) sim[c] = acc * TEMP_INV;
  }
  __syncthreads();

  float m = -3.0e38f;
  for (int c = tid; c < cnt; c += 256) m = fmaxf(m, sim[c]);
#pragma unroll
  for (int off = 32; off; off >>= 1) m = fmaxf(m, __shfl_xor(m, off, 64));
  if (lane == 0) rbuf[wid] = m;
  __syncthreads();
  m = fmaxf(fmaxf(rbuf[0], rbuf[1]), fmaxf(rbuf[2], rbuf[3]));

  float s = 0.f;
  for (int c = tid; c < cnt; c += 256) s += expf(sim[c] - m);
#pragma unroll
  for (int off = 32; off; off >>= 1) s += __shfl_xor(s, off, 64);
  if (lane == 0) rbuf[4 + wid] = s;
  __syncthreads();
  if (tid == 0) {
    float tot = rbuf[4] + rbuf[5] + rbuf[6] + rbuf[7];
    lse_out[row] = m + logf(tot);
  }
}

// ---------------------------------------------------------------------------
// Kernel 4: final scalar. loss = sum_t(mean_k lse) / count(t with any valid).
// ---------------------------------------------------------------------------
__global__ void final_kernel(const float* __restrict__ lse,
                             const int* __restrict__ vcnt,
                             float* __restrict__ out) {
  const int t = threadIdx.x;           // 64 threads, t < 20 active
  float loss = 0.f, flag = 0.f;
  if (t < T_DIM && vcnt[t] > 0) {
    float s = 0.f;
    for (int k = 0; k < K_DIM; ++k) s += lse[t * K_DIM + k];
    loss = s * (1.0f / K_DIM);
    flag = 1.f;
  }
#pragma unroll
  for (int off = 32; off; off >>= 1) {
    loss += __shfl_down(loss, off, 64);
    flag += __shfl_down(flag, off, 64);
  }
  if (t == 0)
    out[0] = (flag > 0.f) ? loss * (1.0f / fmaxf(flag, 1.f)) : 0.f;  // WEIGHT_UWE=1
}

// ---------------------------------------------------------------------------
extern "C" void kernel_launch(void* const* d_in, const int* in_sizes, int n_in,
                              void* d_out, int out_size, void* d_ws, size_t ws_size,
                              hipStream_t stream) {
  const int*   wc   = (const int*)d_in[0];    // time_wordcount [T,V] int32
  const float* beta = (const float*)d_in[1];  // beta [T,K,V] f32
  const float* temb = (const float*)d_in[2];  // topic_embeddings [T,K,D] f32
  const float* wemb = (const float*)d_in[3];  // word_embeddings [V,D] f32

  // ws layout: topk 80000B | vlist 80000B | vcnt 128B | lse 4000B
  char* ws = (char*)d_ws;
  int*   topk_idx = (int*)(ws + 0);
  int*   vlist    = (int*)(ws + 80000);
  int*   vcnt     = (int*)(ws + 160000);
  float* lse      = (float*)(ws + 160128);
  float* out      = (float*)d_out;

  topk_kernel<<<T_DIM * K_DIM, 512, 0, stream>>>(beta, topk_idx);
  build_valid_kernel<<<T_DIM, 512, 0, stream>>>(wc, topk_idx, vlist, vcnt);
  lse_kernel<<<T_DIM * K_DIM, 256, 0, stream>>>(temb, wemb, vlist, vcnt, lse);
  final_kernel<<<1, 64, 0, stream>>>(lse, vcnt, out);
}